// Round 17
// baseline (111.579 us; speedup 1.0000x reference)
//
#include <hip/hip_runtime.h>

#define NCLS    20
#define NB      8
#define MAXDET  300
#define NEGV    (-1e9f)
#define NEGH    (-5e8f)
#define BLKN    512
#define BLKC    1024
#define KTARGET 896       // fallback-path window target
#define KMAX    1024
#define NBIN    256
#define NSLICE  64
#define SLSH    6
#define NSEG    8
#define SEGCAP  128
#define CSTR    16        // counter stride (u32) -> one 64B line per counter
// fixed first-pass score cut: E[count > T0] ~ 430 per (image,class) on U^2 scores.
// Exactness does NOT depend on this value: overflow/shortfall use the exact rescan fallback.
#define T0F     0.98257f

// exact: RN_f32(inter/den) > 0.5  <=>  (double)inter > T_MID * (double)den   (den>0)
#define T_MID   0x1.000001p-1

typedef unsigned long long u64;
typedef unsigned int u32;

__device__ __forceinline__ u64 packkey(float s, int j) {
    // valid scores are positive: bits^0x80000000 order-preserving; ~j -> lower idx wins
    return ((u64)(__float_as_uint(s) ^ 0x80000000u) << 32) | (u32)(~(u32)j);
}
__device__ __forceinline__ u64 wredmax64(u64 k) {
#pragma unroll
    for (int off = 32; off > 0; off >>= 1) {
        u64 o = __shfl_xor(k, off);
        if (o > k) k = o;
    }
    return k;
}
__device__ __forceinline__ int binfull(float s) {
    int full = (int)(s * 262144.0f);
    return full > 262143 ? 262143 : full;
}
__device__ __forceinline__ int bin256(float s) { return binfull(s) >> 10; }

#define OFF_B3D (NB * MAXDET * 4)
#define OFF_SC  (OFF_B3D + NB * MAXDET * 16)
#define OFF_LAB (OFF_SC + NB * MAXDET)

// ---------------- Kernel Z: zero the segment + done counters ----------------
__global__ __launch_bounds__(256) void zero_kernel(u32* __restrict__ p, int nwords)
{
    int i = blockIdx.x * 256 + threadIdx.x;
    if (i < nwords) p[i] = 0;
}

// ---------------- Kernel B: single-pass collect with fixed threshold ----------------
__global__ __launch_bounds__(BLKN) void collect_kernel(
    const float* __restrict__ cls, u64* __restrict__ keys_g, u32* __restrict__ cnt_g, int n)
{
    const int b = blockIdx.x & 7;            // same-image blocks -> same XCD
    const int slice = blockIdx.x >> 3;       // 0..63
    const int seg = slice >> 3;              // 0..7
    const int tid = threadIdx.x;
    const int F4 = (n * NCLS) >> 2;
    const int s0 = (int)(((long)slice * F4) >> SLSH);
    const int s1 = (int)(((long)(slice + 1) * F4) >> SLSH);

    const float4* p4 = (const float4*)(cls + (long)b * n * NCLS);
    for (int q = s0 + tid; q < s1; q += BLKN) {
        float4 v = p4[q];
        int f = q << 2;
        float ss[4] = {v.x, v.y, v.z, v.w};
#pragma unroll
        for (int e = 0; e < 4; ++e) {
            float sc = ss[e];
            if (sc > T0F) {                  // strict >; all such also pass the 0.05 ref filter
                u32 fe = (u32)(f + e);
                u32 c = fe % NCLS;
                int row = (int)(fe / NCLS);
                const int pair = b * NCLS + (int)c;
                u32 slot = atomicAdd(&cnt_g[(pair * NSEG + seg) * CSTR], 1u);
                if (slot < SEGCAP)
                    keys_g[(long)pair * KMAX + (seg << 7) + slot] = packkey(sc, row);
            }
        }
    }
}

// ---------------- hybrid bitonic helpers ----------------
__device__ __forceinline__ u64 cmb(u64 e, u64 p, int i, int jj, int k2) {
    bool up = ((i & k2) == 0);
    bool low = ((i & jj) == 0);
    return (up == low) ? (e > p ? e : p) : (e < p ? e : p);
}
__device__ __forceinline__ void sort1024_1(u64& e, int tid, u64* bufA, u64* bufB) {
    int parity = 0;
    for (int k2 = 2; k2 <= 1024; k2 <<= 1) {
        for (int jj = k2 >> 1; jj > 0; jj >>= 1) {
            if (jj >= 64) {
                u64* buf = parity ? bufB : bufA; parity ^= 1;
                buf[tid] = e;
                __syncthreads();
                u64 p = buf[tid ^ jj];
                e = cmb(e, p, tid, jj, k2);
            } else {
                u64 p = __shfl_xor(e, jj);
                e = cmb(e, p, tid, jj, k2);
            }
        }
    }
    __syncthreads();
    bufA[tid] = e;
    __syncthreads();
}
__device__ __forceinline__ void sort512_1(u64& e, int tid, u64* bufA, u64* bufB) {
    int parity = 0;
    for (int k2 = 2; k2 <= 512; k2 <<= 1) {
        for (int jj = k2 >> 1; jj > 0; jj >>= 1) {
            if (jj >= 64) {
                u64* buf = parity ? bufB : bufA; parity ^= 1;
                if (tid < 512) buf[tid] = e;
                __syncthreads();
                if (tid < 512) { u64 p = buf[tid ^ jj]; e = cmb(e, p, tid, jj, k2); }
            } else {
                if (tid < 512) { u64 p = __shfl_xor(e, jj); e = cmb(e, p, tid, jj, k2); }
            }
        }
    }
    __syncthreads();
    if (tid < 512) bufA[tid] = e;
    __syncthreads();
}

// ---------------- Kernel C: per-pair compact + sort + greedy + (last block) fused topk ----------------
template<bool PRE>
__global__ __launch_bounds__(BLKC, 1) void nms_final_kernel(
    const float4* __restrict__ boxes,
    const float*  __restrict__ cls,
    const float*  __restrict__ b3d,
    const u64* __restrict__ keys_g,
    const u32* __restrict__ cnt_g,
    u32* __restrict__ done_g,
    float* __restrict__ sel_ws, int* __restrict__ idx_ws,
    float* __restrict__ out, int n)
{
    const int b = blockIdx.x & 7;
    const int c = blockIdx.x >> 3;
    const int pair = b * NCLS + c;
    const int tid = threadIdx.x;
    const int lane = tid & 63;
    const int wv = tid >> 6;                 // 0..15

    const float4* bb = boxes + (long)b * n;
    const float* srow = cls + (long)b * n * NCLS + c;   // strided (fallback rounds only)
    float* selp = sel_ws + pair * MAXDET;
    int*   idxp = idx_ws + pair * MAXDET;

    __shared__ u64    keysA[KMAX], keysB[KMAX];   // 16KB
    __shared__ float4 cbox[KMAX];                 // 16KB
    __shared__ float4 aBox[MAXDET];               // 4.8KB
    __shared__ u32    hist256[NBIN];
    __shared__ u32    h512[512];
    __shared__ u32    segc[NSEG];
    __shared__ u32    kb0[64], kb1[64], psupm[2];
    __shared__ u64    wl[16];
    __shared__ int    wts[8], ews[8];
    __shared__ int    ctrl[8];   // 0:B 1:cumAbove 2:cumTotal 3:cntLo 4:cntHi 5:k 6:lastflag
    __shared__ int    outA[MAXDET];
    __shared__ u64    ubk;

    if (PRE && tid < NSEG) segc[tid] = cnt_g[(pair * NSEG + tid) * CSTR];
    if (tid == 0) { ubk = ~0ull; ctrl[5] = 0; }
    if (tid < 64) { kb0[tid] = 0; kb1[tid] = 0; }
    if (tid < 2)  psupm[tid] = 0;
    bool first = true;
    __syncthreads();

    int pre_tot = 0; bool pre_ok = false;
    if (PRE) {
        bool over = false;
#pragma unroll
        for (int s = 0; s < NSEG; ++s) {
            int cv = (int)segc[s];
            pre_tot += cv;
            over = over || (cv > SEGCAP);
        }
        pre_ok = (!over) && (pre_tot > 0);
    }

    while (true) {
        const u64 UB = ubk;
        int trusted, cumTotal;

        if (PRE && first && pre_ok) {
            // ---- fixed-threshold window: scatter-compact, then adaptive sort ----
            cumTotal = 0x7fffffff;
            trusted = pre_tot;
            keysA[tid] = 0;
            __syncthreads();
            {
                const int s = tid >> 7, r = tid & (SEGCAP - 1);
                if (r < (int)segc[s]) {
                    int start = 0;
#pragma unroll
                    for (int q = 0; q < NSEG; ++q) if (q < s) start += (int)segc[q];
                    keysA[start + r] = keys_g[(long)pair * KMAX + tid];
                }
            }
            __syncthreads();
            if (pre_tot <= 512) {
                u64 e = (tid < 512) ? keysA[tid] : 0;
                sort512_1(e, tid, keysA, keysB);
            } else {
                u64 e = keysA[tid];
                sort1024_1(e, tid, keysA, keysB);
            }
        } else {
            // ---- fallback rounds: full strided rescan (exact; covers overflow/empty/shortfall) ----
            if (tid < NBIN) hist256[tid] = 0;
            keysA[tid] = 0;
            if (tid > 0 && tid < 5) ctrl[tid] = 0;
            if (tid == 0) ctrl[0] = -1;
            __syncthreads();
            for (int j = tid; j < n; j += BLKC) {
                float sc = srow[(long)j * NCLS];
                if (sc > 0.05f) { u64 ky = packkey(sc, j); if (ky < UB) atomicAdd(&hist256[bin256(sc)], 1u); }
            }
            __syncthreads();
            if (wv == 0) {
                u32 h0 = hist256[4 * lane], h1 = hist256[4 * lane + 1],
                    h2 = hist256[4 * lane + 2], h3 = hist256[4 * lane + 3];
                int acc = (int)(h0 + h1 + h2 + h3);
#pragma unroll
                for (int d = 1; d < 64; d <<= 1) { int o = __shfl_down(acc, d); if (lane + d < 64) acc += o; }
                int S0 = acc, S1 = S0 - (int)h0, S2 = S1 - (int)h1, S3 = S2 - (int)h2, S4 = S3 - (int)h3;
                if (lane == 0) { ctrl[0] = -1; ctrl[1] = 0; ctrl[2] = S0; }
                int bin = -1, ca = 0;
                if      (S0 >= KTARGET && S1 < KTARGET) { bin = 4 * lane;     ca = S1; }
                else if (S1 >= KTARGET && S2 < KTARGET) { bin = 4 * lane + 1; ca = S2; }
                else if (S2 >= KTARGET && S3 < KTARGET) { bin = 4 * lane + 2; ca = S3; }
                else if (S3 >= KTARGET && S4 < KTARGET) { bin = 4 * lane + 3; ca = S4; }
                if (bin >= 0) { ctrl[0] = bin; ctrl[1] = ca; }
            }
            __syncthreads();
            cumTotal = ctrl[2];
            if (cumTotal == 0) break;
            const int cumAbove = ctrl[1];
            const int B = ctrl[0];
            for (int j = tid; j < n; j += BLKC) {
                float sc = srow[(long)j * NCLS];
                if (sc > 0.05f) {
                    u64 ky = packkey(sc, j);
                    if (ky < UB) {
                        int bn = bin256(sc);
                        if (bn > B) { int sl = atomicAdd(&ctrl[4], 1); if (sl < KMAX) keysA[sl] = ky; }
                        else if (bn == B) {
                            int p = atomicAdd(&ctrl[3], 1);
                            int pos = KMAX - 1 - p;
                            if (pos >= cumAbove) keysA[pos] = ky;
                        }
                    }
                }
            }
            __syncthreads();
            const int cLo = ctrl[3], cHi = ctrl[4];
            const bool dropped = (cHi + cLo) > KMAX;
            trusted = dropped ? cHi : (cHi + cLo);
            if (trusted > 0) {
                u64 e = keysA[tid];
                __syncthreads();
                sort1024_1(e, tid, keysA, keysB);
            } else {
                u64 lb = 0;
                for (int j = tid; j < n; j += BLKC) {
                    float sc = srow[(long)j * NCLS];
                    if (sc > 0.05f) { u64 ky = packkey(sc, j); if (ky < UB && ky > lb) lb = ky; }
                }
                lb = wredmax64(lb);
                if (lane == 0) wl[wv] = lb;
                __syncthreads();
                if (tid == 0) { u64 bk = 0; for (int w = 0; w < 16; ++w) if (wl[w] > bk) bk = wl[w]; keysA[0] = bk; }
                trusted = 1;
                __syncthreads();
            }
        }

        // ---- preload ALL candidate boxes (one wide gather) ----
        {
            u64 ky = (tid < trusted) ? keysA[tid] : 0;
            float4 bx = make_float4(0.f, 0.f, 0.f, 0.f);
            if (tid < trusted) bx = bb[(int)(~(u32)ky)];
            cbox[tid] = bx;
        }
        __syncthreads();

        // ---- greedy over sorted prefix: 2 barriers/chunk ----
        for (int base = 0; base < trusted; base += 64) {
            const int kcur = ctrl[5];
            if (kcur >= MAXDET) break;
            const int ci = base + lane;
            const bool have = ci < trusted;
            const float4 pb = cbox[have ? ci : 0];
            const float par = (pb.z - pb.x) * (pb.w - pb.y);

            bool sup = false;
            for (int a = wv; a < kcur; a += 16) {
                float4 ab = aBox[a];
                float am = (ab.z - ab.x) * (ab.w - ab.y);
                float ltx = fmaxf(ab.x, pb.x), lty = fmaxf(ab.y, pb.y);
                float rbx = fminf(ab.z, pb.z), rby = fminf(ab.w, pb.w);
                float wx = fmaxf(rbx - ltx, 0.0f), wy = fmaxf(rby - lty, 0.0f);
                float inter = wx * wy;
                float den = ((par + am) - inter) + 1e-9f;   // ref op order
                sup = sup || ((double)inter > T_MID * (double)den);
            }
            u64 bal = __ballot(sup && have);
            if (lane == 0 && bal) { atomicOr(&psupm[0], (u32)bal); atomicOr(&psupm[1], (u32)(bal >> 32)); }

#pragma unroll
            for (int r = 0; r < 4; ++r) {
                const int m = (r << 4) | wv;
                if (lane < m && (base + m) < trusted) {
                    float4 vb = cbox[base + m];
                    float va = (vb.z - vb.x) * (vb.w - vb.y);
                    float ltx = fmaxf(pb.x, vb.x), lty = fmaxf(pb.y, vb.y);
                    float rbx = fminf(pb.z, vb.z), rby = fminf(pb.w, vb.w);
                    float wx = fmaxf(rbx - ltx, 0.0f), wy = fmaxf(rby - lty, 0.0f);
                    float inter = wx * wy;
                    float den = ((va + par) - inter) + 1e-9f;  // victim area first (ref order)
                    if ((double)inter > T_MID * (double)den) {
                        if (lane < 32) atomicOr(&kb0[m], 1u << lane);
                        else           atomicOr(&kb1[m], 1u << (lane - 32));
                    }
                }
            }
            __syncthreads();                 // bar 1

            if (tid < 64) {
                const u64 kbm = ((u64)kb1[lane] << 32) | kb0[lane];
                const u64 ps  = ((u64)psupm[1] << 32) | psupm[0];
                const bool alive0 = have && !((ps >> lane) & 1);
                u64 accm = __ballot(alive0);
                for (int it = 0; it < 64; ++it) {
                    u64 nm = __ballot(alive0 && ((kbm & accm) == 0ull));
                    if (nm == accm) break;
                    accm = nm;
                }
                const bool a = (accm >> lane) & 1;
                const int rank = (int)__popcll(accm & ((1ull << lane) - 1ull));
                const int rem = MAXDET - kcur;
                if (a && rank < rem) {
                    const int slot = kcur + rank;
                    aBox[slot] = pb;
                    const u64 ky = keysA[ci];
                    selp[slot] = __uint_as_float((u32)(ky >> 32) ^ 0x80000000u);
                    idxp[slot] = (int)(~(u32)ky);
                }
                kb0[lane] = 0; kb1[lane] = 0;
                if (lane < 2) psupm[lane] = 0;
                if (lane == 0) {
                    const int cnt = (int)__popcll(accm);
                    ctrl[5] = kcur + (cnt < rem ? cnt : rem);
                }
            }
            __syncthreads();                 // bar 2
        }

        if (tid == 0) ubk = keysA[trusted - 1];
        first = false;
        __syncthreads();
        if (ctrl[5] >= MAXDET || cumTotal - trusted <= 0) break;
    }

    const int kfin = ctrl[5];
    for (int f = kfin + tid; f < MAXDET; f += BLKC) { selp[f] = NEGV; idxp[f] = 0; }

    if (done_g == nullptr) return;

    // ---- last-block election: fused per-image top-300 + gather ----
    __threadfence();                         // release sel_ws/idx_ws writes (device scope)
    __syncthreads();
    if (tid == 0) ctrl[6] = (int)atomicAdd(&done_g[b * CSTR], 1u);
    __syncthreads();
    if (ctrl[6] != NCLS - 1) return;
    __threadfence();                         // acquire: all 20 blocks' writes now visible

    const int M = NCLS * MAXDET;             // 6000
    const float* sp = sel_ws + b * M;
    const int*   ip = idx_ws + b * M;

    if (tid < 512) { h512[tid] = 0; keysA[tid] = 0; }
    if (tid > 0 && tid < 8) ctrl[tid] = 0;
    if (tid == 0) { ctrl[0] = -1; ctrl[5] = -1; }
    __syncthreads();

    for (int f = tid; f < M; f += BLKC) {
        float v = sp[f];
        if (v > 0.05f) atomicAdd(&h512[binfull(v) >> 9], 1u);
    }
    __syncthreads();
    {
        const int h = (tid < 512) ? (int)h512[tid] : 0;
        int acc = h;
#pragma unroll
        for (int d = 1; d < 64; d <<= 1) { int o = __shfl_down(acc, d); if (lane + d < 64) acc += o; }
        if (lane == 0 && wv < 8) wts[wv] = acc;
        __syncthreads();
        if (tid < 8) { int e = 0; for (int w = tid + 1; w < 8; ++w) e += wts[w]; ews[tid] = e; }
        __syncthreads();
        if (tid < 512) {
            const int S = acc + ews[wv];
            if (S >= MAXDET && (S - h) < MAXDET) { ctrl[0] = tid; ctrl[1] = S - h; }
            if (tid == 0) ctrl[2] = S;
        }
    }
    __syncthreads();
    const int B1 = ctrl[0];
    const int cA1 = ctrl[1];

    if (tid < 512) h512[tid] = 0;
    __syncthreads();
    if (B1 >= 0) {
        for (int f = tid; f < M; f += BLKC) {
            float v = sp[f];
            if (v > 0.05f) {
                int full = binfull(v);
                if ((full >> 9) == B1) atomicAdd(&h512[full & 511], 1u);
            }
        }
    }
    __syncthreads();
    const int KT2 = MAXDET - cA1;
    {
        const int h = (tid < 512) ? (int)h512[tid] : 0;
        int acc = h;
#pragma unroll
        for (int d = 1; d < 64; d <<= 1) { int o = __shfl_down(acc, d); if (lane + d < 64) acc += o; }
        if (lane == 0 && wv < 8) wts[wv] = acc;
        __syncthreads();
        if (tid < 8) { int e = 0; for (int w = tid + 1; w < 8; ++w) e += wts[w]; ews[tid] = e; }
        __syncthreads();
        if (tid < 512) {
            const int S = acc + ews[wv];
            if (B1 >= 0 && S >= KT2 && (S - h) < KT2) { ctrl[5] = tid; ctrl[6] = S - h; }
        }
    }
    __syncthreads();
    const int B2 = ctrl[5];
    const int cA2 = ctrl[6];

    for (int f = tid; f < M; f += BLKC) {
        float v = sp[f];
        if (v > 0.05f) {
            int full = binfull(v);
            int bkt = full >> 9, sub = full & 511;
            u64 k = packkey(v, f);
            bool hi = (B1 < 0) || (bkt > B1) || (bkt == B1 && sub > B2);
            bool lo = (B1 >= 0) && (bkt == B1) && (sub == B2);
            if (hi) { int slot = atomicAdd(&ctrl[3], 1); if (slot < 512) keysA[slot] = k; }
            else if (lo) { int p = atomicAdd(&ctrl[4], 1); int pos = 511 - p; if (pos >= cA1 + cA2) keysA[pos] = k; }
        }
    }
    __syncthreads();
    const bool tdrop = (ctrl[3] + ctrl[4]) > 512;

    if (!tdrop) {
        u64 e = (tid < 512) ? keysA[tid] : 0;
        sort512_1(e, tid, keysA, keysB);
    } else {
        // exact fallback: 20-way sequential merge on wave 0 (rare)
        if (tid < 64) {
            int pos = 0;
            for (int k = 0; k < MAXDET; ++k) {
                u64 key = 0;
                if (lane < NCLS && pos < MAXDET) {
                    float v = sp[lane * MAXDET + pos];
                    if (v > 0.05f) key = packkey(v, lane * MAXDET + pos);
                }
                u64 r = wredmax64(key);
                if (r != 0) {
                    u64 bal = __ballot(key == r);
                    int w = __ffsll((long long)bal) - 1;
                    if (lane == w) pos++;
                }
                if (lane == 0) keysA[k] = r;
            }
        }
        __syncthreads();
    }

    for (int k = tid; k < MAXDET; k += BLKC) {
        const u64 kk = keysA[k];
        const bool ok = kk != 0;
        const int flat = (int)(~(u32)kk);
        const float sc = __uint_as_float((u32)(kk >> 32) ^ 0x80000000u);
        const int a = ok ? ip[flat] : -1;
        const int cc = flat / MAXDET;
        float4 bx = make_float4(-1.f, -1.f, -1.f, -1.f);
        if (ok) bx = bb[a];
        out[(long)b * MAXDET * 4 + k * 4 + 0] = bx.x;
        out[(long)b * MAXDET * 4 + k * 4 + 1] = bx.y;
        out[(long)b * MAXDET * 4 + k * 4 + 2] = bx.z;
        out[(long)b * MAXDET * 4 + k * 4 + 3] = bx.w;
        out[OFF_SC  + (long)b * MAXDET + k] = ok ? sc : -1.0f;
        out[OFF_LAB + (long)b * MAXDET + k] = ok ? (float)cc : -1.0f;
        outA[k] = a;
    }
    __syncthreads();
    for (int q = tid; q < MAXDET * 16; q += BLKC) {
        const int k = q >> 4;
        const int a = outA[k];
        out[OFF_B3D + (long)b * MAXDET * 16 + q] = (a >= 0) ? b3d[((long)b * n + a) * 16 + (q & 15)] : -1.0f;
    }
}

// ---------------- Kernel D (fallback path only): per-image top-300 + gather ----------------
__global__ __launch_bounds__(1024, 1) void topk_kernel(
    const float4* __restrict__ boxes,
    const float*  __restrict__ b3d,
    const float*  __restrict__ sel_ws,
    const int*    __restrict__ idx_ws,
    float* __restrict__ out,
    int n)
{
    const int b = blockIdx.x;
    const int tid = threadIdx.x;
    const int lane = tid & 63;
    const int M = NCLS * MAXDET;

    __shared__ u64  keysA[512];
    __shared__ int  outA[MAXDET];

    // simple exact path: 20-way sequential merge (fallback only; perf non-critical)
    if (tid < 64) {
        int pos = 0;
        const float* sp = sel_ws + b * M;
        for (int k = 0; k < MAXDET; ++k) {
            u64 key = 0;
            if (lane < NCLS && pos < MAXDET) {
                float v = sp[lane * MAXDET + pos];
                if (v > 0.05f) key = packkey(v, lane * MAXDET + pos);
            }
            u64 r = wredmax64(key);
            if (r != 0) {
                u64 bal = __ballot(key == r);
                int w = __ffsll((long long)bal) - 1;
                if (lane == w) pos++;
            }
            if (lane == 0) keysA[k] = r;
        }
    }
    __syncthreads();

    for (int k = tid; k < MAXDET; k += 1024) {
        const u64 kk = keysA[k];
        const bool ok = kk != 0;
        const int flat = (int)(~(u32)kk);
        const float sc = __uint_as_float((u32)(kk >> 32) ^ 0x80000000u);
        const int a = ok ? idx_ws[b * M + flat] : -1;
        const int cc = flat / MAXDET;
        float4 bx = make_float4(-1.f, -1.f, -1.f, -1.f);
        if (ok) bx = boxes[(long)b * n + a];
        out[(long)b * MAXDET * 4 + k * 4 + 0] = bx.x;
        out[(long)b * MAXDET * 4 + k * 4 + 1] = bx.y;
        out[(long)b * MAXDET * 4 + k * 4 + 2] = bx.z;
        out[(long)b * MAXDET * 4 + k * 4 + 3] = bx.w;
        out[OFF_SC  + (long)b * MAXDET + k] = ok ? sc : -1.0f;
        out[OFF_LAB + (long)b * MAXDET + k] = ok ? (float)cc : -1.0f;
        outA[k] = a;
    }
    __syncthreads();
    for (int q = tid; q < MAXDET * 16; q += 1024) {
        const int k = q >> 4;
        const int a = outA[k];
        out[OFF_B3D + (long)b * MAXDET * 16 + q] = (a >= 0) ? b3d[((long)b * n + a) * 16 + (q & 15)] : -1.0f;
    }
}

extern "C" void kernel_launch(void* const* d_in, const int* in_sizes, int n_in,
                              void* d_out, int out_size, void* d_ws, size_t ws_size,
                              hipStream_t stream)
{
    const float* boxes = (const float*)d_in[0];   // [8, N, 4]
    const float* b3d   = (const float*)d_in[1];   // [8, N, 16]
    const float* cls   = (const float*)d_in[2];   // [8, N, 20]
    float* out = (float*)d_out;

    const int n = in_sizes[0] / (NB * 4);         // 49104
    const int NP = NB * NCLS;                     // 160

    const size_t cntB   = (size_t)NP * NSEG * CSTR * sizeof(u32);            // 80KB
    const size_t doneB  = (size_t)NB * CSTR * sizeof(u32);                   // 512B
    const size_t keysB_ = (size_t)NP * KMAX * sizeof(u64);                   // 1.25MB
    const size_t selB   = (size_t)NP * MAXDET * sizeof(float);

    char* p = (char*)d_ws;
    u32*  cnt_g  = (u32*)p;                p += cntB;    // contiguous zero region: cnt + done
    u32*  done_g = (u32*)p;                p += doneB;
    u64*  keys_g = (u64*)p;                p += keysB_;
    float* sel_ws = (float*)p;             p += selB;
    int*   idx_ws = (int*)p;               p += selB;

    if (ws_size >= (size_t)(p - (char*)d_ws)) {
        const int zwords = (int)((cntB + doneB) / sizeof(u32));
        hipLaunchKernelGGL(zero_kernel, dim3((zwords + 255) / 256), dim3(256), 0, stream,
                           cnt_g, zwords);
        hipLaunchKernelGGL(collect_kernel, dim3(NB * NSLICE), dim3(BLKN), 0, stream,
                           cls, keys_g, cnt_g, n);
        hipLaunchKernelGGL((nms_final_kernel<true>), dim3(NP), dim3(BLKC), 0, stream,
                           (const float4*)boxes, cls, b3d, keys_g, cnt_g, done_g,
                           sel_ws, idx_ws, out, n);
    } else {
        float* sel2 = (float*)d_ws;
        int*   idx2 = (int*)((char*)d_ws + selB);
        hipLaunchKernelGGL((nms_final_kernel<false>), dim3(NP), dim3(BLKC), 0, stream,
                           (const float4*)boxes, cls, b3d, nullptr, nullptr, nullptr,
                           sel2, idx2, out, n);
        hipLaunchKernelGGL(topk_kernel, dim3(NB), dim3(1024), 0, stream,
                           (const float4*)boxes, b3d, sel2, idx2, out, n);
    }
}

// Round 18
// 75.163 us; speedup vs baseline: 1.4845x; 1.4845x over previous
//
#include <hip/hip_runtime.h>

#define NCLS    20
#define NB      8
#define MAXDET  300
#define NEGV    (-1e9f)
#define NEGH    (-5e8f)
#define BLKN    512
#define BLKC    1024
#define KTARGET 896       // fallback-path window target
#define KMAX    1024
#define NBIN    256
#define NSLICE  64
#define SLSH    6
#define NSEG    8
#define SEGCAP  128
#define CSTR    16        // counter stride (u32) -> one 64B line per counter
// fixed first-pass score cut: E[count > T0] ~ 430 per (image,class) on U^2 scores.
// Exactness does NOT depend on this value: overflow/shortfall use the exact rescan fallback.
#define T0F     0.98257f

// exact: RN_f32(inter/den) > 0.5  <=>  (double)inter > T_MID * (double)den   (den>0)
#define T_MID   0x1.000001p-1

typedef unsigned long long u64;
typedef unsigned int u32;

__device__ __forceinline__ u64 packkey(float s, int j) {
    // valid scores are positive: bits^0x80000000 order-preserving; ~j -> lower idx wins
    return ((u64)(__float_as_uint(s) ^ 0x80000000u) << 32) | (u32)(~(u32)j);
}
__device__ __forceinline__ u64 wredmax64(u64 k) {
#pragma unroll
    for (int off = 32; off > 0; off >>= 1) {
        u64 o = __shfl_xor(k, off);
        if (o > k) k = o;
    }
    return k;
}
__device__ __forceinline__ int binfull(float s) {
    int full = (int)(s * 262144.0f);
    return full > 262143 ? 262143 : full;
}
__device__ __forceinline__ int bin256(float s) { return binfull(s) >> 10; }

// ---------------- Kernel Z: zero the segment counters ----------------
__global__ __launch_bounds__(256) void zero_kernel(u32* __restrict__ p, int nwords)
{
    int i = blockIdx.x * 256 + threadIdx.x;
    if (i < nwords) p[i] = 0;
}

// ---------------- Kernel B: single-pass collect with fixed threshold ----------------
__global__ __launch_bounds__(BLKN) void collect_kernel(
    const float* __restrict__ cls, u64* __restrict__ keys_g, u32* __restrict__ cnt_g, int n)
{
    const int b = blockIdx.x & 7;            // same-image blocks -> same XCD
    const int slice = blockIdx.x >> 3;       // 0..63
    const int seg = slice >> 3;              // 0..7
    const int tid = threadIdx.x;
    const int F4 = (n * NCLS) >> 2;
    const int s0 = (int)(((long)slice * F4) >> SLSH);
    const int s1 = (int)(((long)(slice + 1) * F4) >> SLSH);

    const float4* p4 = (const float4*)(cls + (long)b * n * NCLS);
    for (int q = s0 + tid; q < s1; q += BLKN) {
        float4 v = p4[q];
        int f = q << 2;
        float ss[4] = {v.x, v.y, v.z, v.w};
#pragma unroll
        for (int e = 0; e < 4; ++e) {
            float sc = ss[e];
            if (sc > T0F) {                  // strict >; all such also pass the 0.05 ref filter
                u32 fe = (u32)(f + e);
                u32 c = fe % NCLS;
                int row = (int)(fe / NCLS);
                const int pair = b * NCLS + (int)c;
                u32 slot = atomicAdd(&cnt_g[(pair * NSEG + seg) * CSTR], 1u);
                if (slot < SEGCAP)
                    keys_g[(long)pair * KMAX + (seg << 7) + slot] = packkey(sc, row);
            }
        }
    }
}

// ---------------- hybrid bitonic helpers ----------------
__device__ __forceinline__ u64 cmb(u64 e, u64 p, int i, int jj, int k2) {
    bool up = ((i & k2) == 0);
    bool low = ((i & jj) == 0);
    return (up == low) ? (e > p ? e : p) : (e < p ? e : p);
}
// 1024 u64, 1/thread, 1024 threads
__device__ __forceinline__ void sort1024_1(u64& e, int tid, u64* bufA, u64* bufB) {
    int parity = 0;
    for (int k2 = 2; k2 <= 1024; k2 <<= 1) {
        for (int jj = k2 >> 1; jj > 0; jj >>= 1) {
            if (jj >= 64) {
                u64* buf = parity ? bufB : bufA; parity ^= 1;
                buf[tid] = e;
                __syncthreads();
                u64 p = buf[tid ^ jj];
                e = cmb(e, p, tid, jj, k2);
            } else {
                u64 p = __shfl_xor(e, jj);
                e = cmb(e, p, tid, jj, k2);
            }
        }
    }
    __syncthreads();
    bufA[tid] = e;                 // final sorted array -> bufA
    __syncthreads();
}
// 512 u64, tid<512 active (block may be 1024 wide)
__device__ __forceinline__ void sort512_1(u64& e, int tid, u64* bufA, u64* bufB) {
    int parity = 0;
    for (int k2 = 2; k2 <= 512; k2 <<= 1) {
        for (int jj = k2 >> 1; jj > 0; jj >>= 1) {
            if (jj >= 64) {
                u64* buf = parity ? bufB : bufA; parity ^= 1;
                if (tid < 512) buf[tid] = e;
                __syncthreads();
                if (tid < 512) { u64 p = buf[tid ^ jj]; e = cmb(e, p, tid, jj, k2); }
            } else {
                if (tid < 512) { u64 p = __shfl_xor(e, jj); e = cmb(e, p, tid, jj, k2); }
            }
        }
    }
    __syncthreads();
    if (tid < 512) bufA[tid] = e;
    __syncthreads();
}

// ---------------- Kernel C: per-pair compact + adaptive sort + greedy (reference-exact) ----------------
template<bool PRE>
__global__ __launch_bounds__(BLKC, 1) void nms_final_kernel(
    const float4* __restrict__ boxes,
    const float*  __restrict__ cls,
    const u64* __restrict__ keys_g,
    const u32* __restrict__ cnt_g,
    float* __restrict__ sel_ws, int* __restrict__ idx_ws, int n)
{
    const int b = blockIdx.x & 7;
    const int c = blockIdx.x >> 3;
    const int pair = b * NCLS + c;
    const int tid = threadIdx.x;
    const int lane = tid & 63;
    const int wv = tid >> 6;                 // 0..15

    const float4* bb = boxes + (long)b * n;
    const float* srow = cls + (long)b * n * NCLS + c;   // strided (fallback rounds only)
    float* selp = sel_ws + pair * MAXDET;
    int*   idxp = idx_ws + pair * MAXDET;

    __shared__ u64    keysA[KMAX], keysB[KMAX];   // 16KB
    __shared__ float4 cbox[KMAX];                 // 16KB
    __shared__ float4 aBox[MAXDET];               // 4.8KB
    __shared__ u32    hist256[NBIN];
    __shared__ u32    segc[NSEG];
    __shared__ u32    kb0[64], kb1[64], psupm[2];
    __shared__ u64    wl[16];
    __shared__ int    ctrl[8];   // 0:B 1:cumAbove 2:cumTotal 3:cntLo 4:cntHi 5:k
    __shared__ u64    ubk;

    if (PRE && tid < NSEG) segc[tid] = cnt_g[(pair * NSEG + tid) * CSTR];
    if (tid == 0) { ubk = ~0ull; ctrl[5] = 0; }
    if (tid < 64) { kb0[tid] = 0; kb1[tid] = 0; }
    if (tid < 2)  psupm[tid] = 0;
    bool first = true;
    __syncthreads();

    int pre_tot = 0; bool pre_ok = false;
    if (PRE) {
        bool over = false;
#pragma unroll
        for (int s = 0; s < NSEG; ++s) {
            int cv = (int)segc[s];
            pre_tot += cv;
            over = over || (cv > SEGCAP);
        }
        pre_ok = (!over) && (pre_tot > 0);
    }

    while (true) {
        const u64 UB = ubk;
        int trusted, cumTotal;

        if (PRE && first && pre_ok) {
            // ---- fixed-threshold window: scatter-compact, then adaptive sort ----
            cumTotal = 0x7fffffff;           // unknown remaining; exit on k>=MAXDET or next-round path
            trusted = pre_tot;
            keysA[tid] = 0;
            __syncthreads();
            {
                const int s = tid >> 7, r = tid & (SEGCAP - 1);
                if (r < (int)segc[s]) {
                    int start = 0;
#pragma unroll
                    for (int q = 0; q < NSEG; ++q) if (q < s) start += (int)segc[q];
                    keysA[start + r] = keys_g[(long)pair * KMAX + tid];
                }
            }
            __syncthreads();
            if (pre_tot <= 512) {
                u64 e = (tid < 512) ? keysA[tid] : 0;
                sort512_1(e, tid, keysA, keysB);
            } else {
                u64 e = keysA[tid];
                sort1024_1(e, tid, keysA, keysB);
            }
        } else {
            // ---- fallback rounds: full strided rescan (exact; covers overflow/empty/shortfall) ----
            if (tid < NBIN) hist256[tid] = 0;
            keysA[tid] = 0;
            if (tid > 0 && tid < 5) ctrl[tid] = 0;
            if (tid == 0) ctrl[0] = -1;
            __syncthreads();
            for (int j = tid; j < n; j += BLKC) {
                float sc = srow[(long)j * NCLS];
                if (sc > 0.05f) { u64 ky = packkey(sc, j); if (ky < UB) atomicAdd(&hist256[bin256(sc)], 1u); }
            }
            __syncthreads();
            if (wv == 0) {
                u32 h0 = hist256[4 * lane], h1 = hist256[4 * lane + 1],
                    h2 = hist256[4 * lane + 2], h3 = hist256[4 * lane + 3];
                int acc = (int)(h0 + h1 + h2 + h3);
#pragma unroll
                for (int d = 1; d < 64; d <<= 1) { int o = __shfl_down(acc, d); if (lane + d < 64) acc += o; }
                int S0 = acc, S1 = S0 - (int)h0, S2 = S1 - (int)h1, S3 = S2 - (int)h2, S4 = S3 - (int)h3;
                if (lane == 0) { ctrl[0] = -1; ctrl[1] = 0; ctrl[2] = S0; }
                int bin = -1, ca = 0;
                if      (S0 >= KTARGET && S1 < KTARGET) { bin = 4 * lane;     ca = S1; }
                else if (S1 >= KTARGET && S2 < KTARGET) { bin = 4 * lane + 1; ca = S2; }
                else if (S2 >= KTARGET && S3 < KTARGET) { bin = 4 * lane + 2; ca = S3; }
                else if (S3 >= KTARGET && S4 < KTARGET) { bin = 4 * lane + 3; ca = S4; }
                if (bin >= 0) { ctrl[0] = bin; ctrl[1] = ca; }
            }
            __syncthreads();
            cumTotal = ctrl[2];
            if (cumTotal == 0) break;
            const int cumAbove = ctrl[1];
            const int B = ctrl[0];
            for (int j = tid; j < n; j += BLKC) {
                float sc = srow[(long)j * NCLS];
                if (sc > 0.05f) {
                    u64 ky = packkey(sc, j);
                    if (ky < UB) {
                        int bn = bin256(sc);
                        if (bn > B) { int sl = atomicAdd(&ctrl[4], 1); if (sl < KMAX) keysA[sl] = ky; }
                        else if (bn == B) {
                            int p = atomicAdd(&ctrl[3], 1);
                            int pos = KMAX - 1 - p;
                            if (pos >= cumAbove) keysA[pos] = ky;
                        }
                    }
                }
            }
            __syncthreads();
            const int cLo = ctrl[3], cHi = ctrl[4];
            const bool dropped = (cHi + cLo) > KMAX;
            trusted = dropped ? cHi : (cHi + cLo);
            if (trusted > 0) {
                u64 e = keysA[tid];
                __syncthreads();
                sort1024_1(e, tid, keysA, keysB);
            } else {
                // boundary overflow w/ empty hi region: single best key < UB (progress)
                u64 lb = 0;
                for (int j = tid; j < n; j += BLKC) {
                    float sc = srow[(long)j * NCLS];
                    if (sc > 0.05f) { u64 ky = packkey(sc, j); if (ky < UB && ky > lb) lb = ky; }
                }
                lb = wredmax64(lb);
                if (lane == 0) wl[wv] = lb;
                __syncthreads();
                if (tid == 0) { u64 bk = 0; for (int w = 0; w < 16; ++w) if (wl[w] > bk) bk = wl[w]; keysA[0] = bk; }
                trusted = 1;
                __syncthreads();
            }
        }

        // ---- preload ALL candidate boxes (one wide gather) ----
        {
            u64 ky = (tid < trusted) ? keysA[tid] : 0;
            float4 bx = make_float4(0.f, 0.f, 0.f, 0.f);
            if (tid < trusted) bx = bb[(int)(~(u32)ky)];
            cbox[tid] = bx;
        }
        __syncthreads();

        // ---- greedy over sorted prefix: 2 barriers/chunk ----
        for (int base = 0; base < trusted; base += 64) {
            const int kcur = ctrl[5];        // uniform (after barrier)
            if (kcur >= MAXDET) break;
            const int ci = base + lane;
            const bool have = ci < trusted;
            const float4 pb = cbox[have ? ci : 0];
            const float par = (pb.z - pb.x) * (pb.w - pb.y);

            // (a) candidate vs prior accepted, split across 16 waves; exact f64 cmp
            bool sup = false;
            for (int a = wv; a < kcur; a += 16) {
                float4 ab = aBox[a];
                float am = (ab.z - ab.x) * (ab.w - ab.y);
                float ltx = fmaxf(ab.x, pb.x), lty = fmaxf(ab.y, pb.y);
                float rbx = fminf(ab.z, pb.z), rby = fminf(ab.w, pb.w);
                float wx = fmaxf(rbx - ltx, 0.0f), wy = fmaxf(rby - lty, 0.0f);
                float inter = wx * wy;
                float den = ((par + am) - inter) + 1e-9f;   // ref op order
                sup = sup || ((double)inter > T_MID * (double)den);
            }
            u64 bal = __ballot(sup && have);
            if (lane == 0 && bal) { atomicOr(&psupm[0], (u32)bal); atomicOr(&psupm[1], (u32)(bal >> 32)); }

            // (b) in-chunk kill matrix: killer=lane, victim m; 16 waves x 4 victims
#pragma unroll
            for (int r = 0; r < 4; ++r) {
                const int m = (r << 4) | wv;
                if (lane < m && (base + m) < trusted) {
                    float4 vb = cbox[base + m];
                    float va = (vb.z - vb.x) * (vb.w - vb.y);
                    float ltx = fmaxf(pb.x, vb.x), lty = fmaxf(pb.y, vb.y);
                    float rbx = fminf(pb.z, vb.z), rby = fminf(pb.w, vb.w);
                    float wx = fmaxf(rbx - ltx, 0.0f), wy = fmaxf(rby - lty, 0.0f);
                    float inter = wx * wy;
                    float den = ((va + par) - inter) + 1e-9f;  // victim area first (ref order)
                    if ((double)inter > T_MID * (double)den) {
                        if (lane < 32) atomicOr(&kb0[m], 1u << lane);
                        else           atomicOr(&kb1[m], 1u << (lane - 32));
                    }
                }
            }
            __syncthreads();                 // bar 1

            // (c) wave 0: ballot fixpoint (== sequential greedy), accept, clear masks
            if (tid < 64) {
                const u64 kbm = ((u64)kb1[lane] << 32) | kb0[lane];
                const u64 ps  = ((u64)psupm[1] << 32) | psupm[0];
                const bool alive0 = have && !((ps >> lane) & 1);
                u64 accm = __ballot(alive0);
                for (int it = 0; it < 64; ++it) {
                    u64 nm = __ballot(alive0 && ((kbm & accm) == 0ull));
                    if (nm == accm) break;
                    accm = nm;
                }
                const bool a = (accm >> lane) & 1;
                const int rank = (int)__popcll(accm & ((1ull << lane) - 1ull));
                const int rem = MAXDET - kcur;
                if (a && rank < rem) {
                    const int slot = kcur + rank;
                    aBox[slot] = pb;
                    const u64 ky = keysA[ci];
                    selp[slot] = __uint_as_float((u32)(ky >> 32) ^ 0x80000000u);
                    idxp[slot] = (int)(~(u32)ky);
                }
                kb0[lane] = 0; kb1[lane] = 0;
                if (lane < 2) psupm[lane] = 0;
                if (lane == 0) {
                    const int cnt = (int)__popcll(accm);
                    ctrl[5] = kcur + (cnt < rem ? cnt : rem);
                }
            }
            __syncthreads();                 // bar 2
        }

        if (tid == 0) ubk = keysA[trusted - 1];
        first = false;
        __syncthreads();
        if (ctrl[5] >= MAXDET || cumTotal - trusted <= 0) break;
    }

    const int kfin = ctrl[5];
    for (int f = kfin + tid; f < MAXDET; f += BLKC) { selp[f] = NEGV; idxp[f] = 0; }
}

// ---------------- Kernel D: per-image global top-300 via 2-level select + gather ----------------
#define OFF_B3D (NB * MAXDET * 4)
#define OFF_SC  (OFF_B3D + NB * MAXDET * 16)
#define OFF_LAB (OFF_SC + NB * MAXDET)

__global__ __launch_bounds__(1024, 1) void topk_kernel(
    const float4* __restrict__ boxes,
    const float*  __restrict__ b3d,
    const float*  __restrict__ sel_ws,
    const int*    __restrict__ idx_ws,
    float* __restrict__ out,
    int n)
{
    const int b = blockIdx.x;
    const int tid = threadIdx.x;
    const int lane = tid & 63;
    const int wv = tid >> 6;                  // 0..15
    const int M = NCLS * MAXDET;              // 6000

    __shared__ u64  kall[NCLS * MAXDET];      // 48KB
    __shared__ u32  h1[512];
    __shared__ u64  keysA[512], keysB[512];
    __shared__ int  wts[8], ews[8];
    __shared__ int  ctrl[8];
    __shared__ int  outA[MAXDET];

    const float* sp = sel_ws + b * M;
    for (int f = tid; f < M; f += 1024) {
        float v = sp[f];
        kall[f] = (v > 0.05f) ? packkey(v, f) : 0ull;
    }
    if (tid < 512) { h1[tid] = 0; keysA[tid] = 0; }
    if (tid > 0 && tid < 8) ctrl[tid] = 0;
    if (tid == 0) { ctrl[0] = -1; ctrl[5] = -1; }
    __syncthreads();

    for (int f = tid; f < M; f += 1024) {
        u64 k = kall[f];
        if (k) {
            float s = __uint_as_float((u32)(k >> 32) ^ 0x80000000u);
            atomicAdd(&h1[binfull(s) >> 9], 1u);
        }
    }
    __syncthreads();
    {
        const int h = (tid < 512) ? (int)h1[tid] : 0;
        int acc = h;
#pragma unroll
        for (int d = 1; d < 64; d <<= 1) { int o = __shfl_down(acc, d); if (lane + d < 64) acc += o; }
        if (lane == 0 && wv < 8) wts[wv] = acc;
        __syncthreads();
        if (tid < 8) { int e = 0; for (int w = tid + 1; w < 8; ++w) e += wts[w]; ews[tid] = e; }
        __syncthreads();
        if (tid < 512) {
            const int S = acc + ews[wv];
            if (S >= MAXDET && (S - h) < MAXDET) { ctrl[0] = tid; ctrl[1] = S - h; }
            if (tid == 0) ctrl[2] = S;
        }
    }
    __syncthreads();
    const int B1 = ctrl[0];
    const int cA1 = ctrl[1];

    if (tid < 512) h1[tid] = 0;
    __syncthreads();
    if (B1 >= 0) {
        for (int f = tid; f < M; f += 1024) {
            u64 k = kall[f];
            if (k) {
                float s = __uint_as_float((u32)(k >> 32) ^ 0x80000000u);
                int full = binfull(s);
                if ((full >> 9) == B1) atomicAdd(&h1[full & 511], 1u);
            }
        }
    }
    __syncthreads();
    const int KT2 = MAXDET - cA1;
    {
        const int h = (tid < 512) ? (int)h1[tid] : 0;
        int acc = h;
#pragma unroll
        for (int d = 1; d < 64; d <<= 1) { int o = __shfl_down(acc, d); if (lane + d < 64) acc += o; }
        if (lane == 0 && wv < 8) wts[wv] = acc;
        __syncthreads();
        if (tid < 8) { int e = 0; for (int w = tid + 1; w < 8; ++w) e += wts[w]; ews[tid] = e; }
        __syncthreads();
        if (tid < 512) {
            const int S = acc + ews[wv];
            if (B1 >= 0 && S >= KT2 && (S - h) < KT2) { ctrl[5] = tid; ctrl[6] = S - h; }
        }
    }
    __syncthreads();
    const int B2 = ctrl[5];
    const int cA2 = ctrl[6];

    for (int f = tid; f < M; f += 1024) {
        u64 k = kall[f];
        if (k) {
            float s = __uint_as_float((u32)(k >> 32) ^ 0x80000000u);
            int full = binfull(s);
            int bkt = full >> 9, sub = full & 511;
            bool hi = (B1 < 0) || (bkt > B1) || (bkt == B1 && sub > B2);
            bool lo = (B1 >= 0) && (bkt == B1) && (sub == B2);
            if (hi) { int slot = atomicAdd(&ctrl[3], 1); if (slot < 512) keysA[slot] = k; }
            else if (lo) { int p = atomicAdd(&ctrl[4], 1); int pos = 511 - p; if (pos >= cA1 + cA2) keysA[pos] = k; }
        }
    }
    __syncthreads();
    const bool dropped = (ctrl[3] + ctrl[4]) > 512;

    if (!dropped) {
        u64 e = (tid < 512) ? keysA[tid] : 0;
        int parity = 0;
        for (int k2 = 2; k2 <= 512; k2 <<= 1) {
            for (int jj = k2 >> 1; jj > 0; jj >>= 1) {
                if (jj >= 64) {
                    u64* buf = parity ? keysB : keysA; parity ^= 1;
                    if (tid < 512) buf[tid] = e;
                    __syncthreads();
                    if (tid < 512) { u64 p = buf[tid ^ jj]; e = cmb(e, p, tid, jj, k2); }
                } else {
                    if (tid < 512) { u64 p = __shfl_xor(e, jj); e = cmb(e, p, tid, jj, k2); }
                }
            }
        }
        __syncthreads();
        if (tid < 512) keysA[tid] = e;
        __syncthreads();
    } else {
        if (tid < 64) {
            int pos = 0;
            for (int k = 0; k < MAXDET; ++k) {
                u64 key = 0;
                if (lane < NCLS && pos < MAXDET) key = kall[lane * MAXDET + pos];
                u64 r = wredmax64(key);
                if (r != 0) {
                    u64 bal = __ballot(key == r);
                    int w = __ffsll((long long)bal) - 1;
                    if (lane == w) pos++;
                }
                if (lane == 0) keysA[k] = r;
            }
        }
        __syncthreads();
    }

    for (int k = tid; k < MAXDET; k += 1024) {
        const u64 kk = keysA[k];
        const bool ok = kk != 0;
        const int flat = (int)(~(u32)kk);
        const float sc = __uint_as_float((u32)(kk >> 32) ^ 0x80000000u);
        const int a = ok ? idx_ws[b * M + flat] : -1;
        const int cc = flat / MAXDET;
        float4 bx = make_float4(-1.f, -1.f, -1.f, -1.f);
        if (ok) bx = boxes[(long)b * n + a];
        out[(long)b * MAXDET * 4 + k * 4 + 0] = bx.x;
        out[(long)b * MAXDET * 4 + k * 4 + 1] = bx.y;
        out[(long)b * MAXDET * 4 + k * 4 + 2] = bx.z;
        out[(long)b * MAXDET * 4 + k * 4 + 3] = bx.w;
        out[OFF_SC  + (long)b * MAXDET + k] = ok ? sc : -1.0f;
        out[OFF_LAB + (long)b * MAXDET + k] = ok ? (float)cc : -1.0f;
        outA[k] = a;
    }
    __syncthreads();
    for (int q = tid; q < MAXDET * 16; q += 1024) {
        const int k = q >> 4;
        const int a = outA[k];
        out[OFF_B3D + (long)b * MAXDET * 16 + q] = (a >= 0) ? b3d[((long)b * n + a) * 16 + (q & 15)] : -1.0f;
    }
}

extern "C" void kernel_launch(void* const* d_in, const int* in_sizes, int n_in,
                              void* d_out, int out_size, void* d_ws, size_t ws_size,
                              hipStream_t stream)
{
    const float* boxes = (const float*)d_in[0];   // [8, N, 4]
    const float* b3d   = (const float*)d_in[1];   // [8, N, 16]
    const float* cls   = (const float*)d_in[2];   // [8, N, 20]
    float* out = (float*)d_out;

    const int n = in_sizes[0] / (NB * 4);         // 49104
    const int NP = NB * NCLS;                     // 160

    const size_t cntB   = (size_t)NP * NSEG * CSTR * sizeof(u32);            // 80KB
    const size_t keysB_ = (size_t)NP * KMAX * sizeof(u64);                   // 1.25MB
    const size_t selB   = (size_t)NP * MAXDET * sizeof(float);

    char* p = (char*)d_ws;
    u32*  cnt_g  = (u32*)p;                p += cntB;
    u64*  keys_g = (u64*)p;                p += keysB_;
    float* sel_ws = (float*)p;             p += selB;
    int*   idx_ws = (int*)p;               p += selB;

    if (ws_size >= (size_t)(p - (char*)d_ws)) {
        const int zwords = (int)(cntB / sizeof(u32));
        hipLaunchKernelGGL(zero_kernel, dim3((zwords + 255) / 256), dim3(256), 0, stream,
                           cnt_g, zwords);
        hipLaunchKernelGGL(collect_kernel, dim3(NB * NSLICE), dim3(BLKN), 0, stream,
                           cls, keys_g, cnt_g, n);
        hipLaunchKernelGGL((nms_final_kernel<true>), dim3(NP), dim3(BLKC), 0, stream,
                           (const float4*)boxes, cls, keys_g, cnt_g, sel_ws, idx_ws, n);
        hipLaunchKernelGGL(topk_kernel, dim3(NB), dim3(1024), 0, stream,
                           (const float4*)boxes, b3d, sel_ws, idx_ws, out, n);
    } else {
        float* sel2 = (float*)d_ws;
        int*   idx2 = (int*)((char*)d_ws + selB);
        hipLaunchKernelGGL((nms_final_kernel<false>), dim3(NP), dim3(BLKC), 0, stream,
                           (const float4*)boxes, cls, nullptr, nullptr, sel2, idx2, n);
        hipLaunchKernelGGL(topk_kernel, dim3(NB), dim3(1024), 0, stream,
                           (const float4*)boxes, b3d, sel2, idx2, out, n);
    }
}